// Round 6
// baseline (495.574 us; speedup 1.0000x reference)
//
#include <hip/hip_runtime.h>
#include <hip/hip_bf16.h>
#include <limits.h>
#include <math.h>

#define NSEG 200
#define STRENGTH 1e-3f
#define NB 4096                 // coarse buckets per segment
#define LOG_NB 12
#define M_TOT (NSEG * NB)
#define HCHUNK 8192             // elements per hist/scatter block
#define WIN 128                 // nominal elements per emd window (bucket-aligned)
#define LOG_WIN 7

__device__ __forceinline__ int bucket_of(float x, float scale) {
    float t = (x + 6.0f) * scale;   // scale = NB/12
    int b = (int)floorf(t);
    b = b < 0 ? 0 : (b > NB - 1 ? NB - 1 : b);
    return b;
}

// ---- 0. segment boundaries from sorted seg ids + zero counts/segSums ----
__global__ void k_bounds(const int* __restrict__ seg, int* __restrict__ seg_starts,
                         int* __restrict__ counts, float* __restrict__ segSums, int N) {
    int stride = gridDim.x * blockDim.x;
    int tid = blockIdx.x * blockDim.x + threadIdx.x;
    for (int k = tid; k < M_TOT; k += stride) counts[k] = 0;
    for (int k = tid; k < NSEG; k += stride) segSums[k] = 0.f;
    if (tid == 0) { seg_starts[0] = 0; seg_starts[NSEG] = N; }
    const int4* s4 = (const int4*)seg;
    int N4 = N >> 2;
    for (int i = tid; i < N4; i += stride) {
        int4 s = s4[i];
        int prev = (i == 0) ? s.x : seg[i * 4 - 1];
        if (s.x != prev) seg_starts[s.x] = i * 4;
        if (s.y != s.x) seg_starts[s.y] = i * 4 + 1;
        if (s.z != s.y) seg_starts[s.z] = i * 4 + 2;
        if (s.w != s.z) seg_starts[s.w] = i * 4 + 3;
    }
}

// ---- 1. histogram of (segment, bucket) via per-block LDS hist ----
__global__ void __launch_bounds__(512)
k_hist(const float* __restrict__ x, const int* __restrict__ seg_starts,
       int* __restrict__ counts, int N, float scale) {
    __shared__ int h[2 * NB];
    __shared__ int sst[NSEG + 1];
    int t = threadIdx.x;
    for (int k = t; k < NSEG + 1; k += 512) sst[k] = seg_starts[k];
    for (int k = t; k < 2 * NB; k += 512) h[k] = 0;
    __syncthreads();
    int base = blockIdx.x * HCHUNK;
    int lo = 0, hi = NSEG - 1;
    while (lo < hi) { int mid = (lo + hi) >> 1; if (base < sst[mid + 1]) hi = mid; else lo = mid + 1; }
    int s0 = lo, bnd = sst[lo + 1];
    const float4* x4 = (const float4*)x;
    for (int it = 0; it < HCHUNK / (512 * 4); ++it) {
        int j = (it * 512 + t) * 4;
        int gi = base + j;
        if (gi < N) {
            float4 v = x4[(base >> 2) + it * 512 + t];
            int sel0 = (gi + 0) >= bnd ? NB : 0;
            int sel1 = (gi + 1) >= bnd ? NB : 0;
            int sel2 = (gi + 2) >= bnd ? NB : 0;
            int sel3 = (gi + 3) >= bnd ? NB : 0;
            atomicAdd(&h[sel0 + bucket_of(v.x, scale)], 1);
            atomicAdd(&h[sel1 + bucket_of(v.y, scale)], 1);
            atomicAdd(&h[sel2 + bucket_of(v.z, scale)], 1);
            atomicAdd(&h[sel3 + bucket_of(v.w, scale)], 1);
        }
    }
    __syncthreads();
    for (int k = t; k < 2 * NB; k += 512) {
        int c = h[k];
        if (c > 0) atomicAdd(&counts[(s0 + (k >= NB)) * NB + (k & (NB - 1))], c);
    }
}

// ---- 2. exclusive scan over M_TOT counters ----
__global__ void k_scan_partial(const int* __restrict__ counts, int* __restrict__ partials, int M) {
    __shared__ int sdata[256];
    int base = blockIdx.x * 2048;
    int sum = 0;
    for (int k = threadIdx.x; k < 2048; k += 256) {
        int idx = base + k;
        sum += (idx < M) ? counts[idx] : 0;
    }
    sdata[threadIdx.x] = sum;
    __syncthreads();
    for (int off = 128; off > 0; off >>= 1) {
        if (threadIdx.x < off) sdata[threadIdx.x] += sdata[threadIdx.x + off];
        __syncthreads();
    }
    if (threadIdx.x == 0) partials[blockIdx.x] = sdata[0];
}

__global__ void k_scan_carry(int* __restrict__ partials, int nb) {
    __shared__ int bufA[1024], bufB[1024];
    int t = threadIdx.x;
    int v = (t < nb) ? partials[t] : 0;
    int* src = bufA; int* dst = bufB;
    src[t] = v;
    __syncthreads();
    for (int off = 1; off < 1024; off <<= 1) {
        dst[t] = src[t] + ((t >= off) ? src[t - off] : 0);
        __syncthreads();
        int* tmp = src; src = dst; dst = tmp;
    }
    if (t < nb) partials[t] = src[t] - v;   // exclusive
}

__global__ void k_scan_final(const int* __restrict__ counts, const int* __restrict__ partials,
                             int* __restrict__ cursor, int* __restrict__ seg_ends,
                             int* __restrict__ win_i, int M) {
    __shared__ int tile[2048];
    __shared__ int sa[256], sb[256];
    int t = threadIdx.x;
    int base = blockIdx.x * 2048;
    for (int k = t; k < 2048; k += 256) {
        int idx = base + k;
        tile[k] = (idx < M) ? counts[idx] : 0;
    }
    __syncthreads();
    int loc[8]; int run = 0;
    for (int k = 0; k < 8; ++k) { loc[k] = run; run += tile[t * 8 + k]; }
    int v = run;
    int* src = sa; int* dst = sb;
    __syncthreads();
    src[t] = v;
    __syncthreads();
    for (int off = 1; off < 256; off <<= 1) {
        int w = src[t] + ((t >= off) ? src[t - off] : 0);
        dst[t] = w;
        __syncthreads();
        int* tmp = src; src = dst; dst = tmp;
    }
    int texcl = src[t] - v;
    int gbase = partials[blockIdx.x];
    for (int k = 0; k < 8; ++k) {
        int idx = base + t * 8 + k;
        if (idx < M) {
            int cnt = tile[t * 8 + k];
            int excl = gbase + texcl + loc[k];
            cursor[idx] = excl;
            if (((idx + 1) & (NB - 1)) == 0)
                seg_ends[((idx + 1) >> LOG_NB) - 1] = excl + cnt;
            // window table: win_i[w] = bucket containing element w*WIN-1
            int wfirst = (excl >> LOG_WIN) + 1;
            int wlast = (excl + cnt) >> LOG_WIN;
            for (int w = wfirst; w <= wlast; ++w) win_i[w] = idx;
        }
    }
}

// ---- 3. scatter with per-block reservation (cursor: starts -> ends) ----
__global__ void __launch_bounds__(512)
k_scatter(const float* __restrict__ x, const int* __restrict__ seg_starts,
          int* __restrict__ cursor, float* __restrict__ sx, int N, float scale) {
    __shared__ int h[2 * NB];
    __shared__ unsigned short lr[HCHUNK];
    __shared__ int sst[NSEG + 1];
    int t = threadIdx.x;
    for (int k = t; k < NSEG + 1; k += 512) sst[k] = seg_starts[k];
    for (int k = t; k < 2 * NB; k += 512) h[k] = 0;
    __syncthreads();
    int base = blockIdx.x * HCHUNK;
    int lo = 0, hi = NSEG - 1;
    while (lo < hi) { int mid = (lo + hi) >> 1; if (base < sst[mid + 1]) hi = mid; else lo = mid + 1; }
    int s0 = lo, bnd = sst[lo + 1];
    const float4* x4 = (const float4*)x;
    // pass 1: local ranks
    for (int it = 0; it < HCHUNK / (512 * 4); ++it) {
        int j = (it * 512 + t) * 4;
        int gi = base + j;
        if (gi < N) {
            float4 v = x4[(base >> 2) + it * 512 + t];
            int g0 = ((gi + 0) >= bnd ? NB : 0) + bucket_of(v.x, scale);
            int g1 = ((gi + 1) >= bnd ? NB : 0) + bucket_of(v.y, scale);
            int g2 = ((gi + 2) >= bnd ? NB : 0) + bucket_of(v.z, scale);
            int g3 = ((gi + 3) >= bnd ? NB : 0) + bucket_of(v.w, scale);
            lr[j + 0] = (unsigned short)atomicAdd(&h[g0], 1);
            lr[j + 1] = (unsigned short)atomicAdd(&h[g1], 1);
            lr[j + 2] = (unsigned short)atomicAdd(&h[g2], 1);
            lr[j + 3] = (unsigned short)atomicAdd(&h[g3], 1);
        }
    }
    __syncthreads();
    // reserve: h[k] becomes global base for this block's (seg,bucket) group
    for (int k = t; k < 2 * NB; k += 512) {
        int c = h[k];
        if (c > 0) h[k] = atomicAdd(&cursor[(s0 + (k >= NB)) * NB + (k & (NB - 1))], c);
    }
    __syncthreads();
    // pass 2: write
    for (int it = 0; it < HCHUNK / (512 * 4); ++it) {
        int j = (it * 512 + t) * 4;
        int gi = base + j;
        if (gi < N) {
            float4 v = x4[(base >> 2) + it * 512 + t];
            int g0 = ((gi + 0) >= bnd ? NB : 0) + bucket_of(v.x, scale);
            int g1 = ((gi + 1) >= bnd ? NB : 0) + bucket_of(v.y, scale);
            int g2 = ((gi + 2) >= bnd ? NB : 0) + bucket_of(v.z, scale);
            int g3 = ((gi + 3) >= bnd ? NB : 0) + bucket_of(v.w, scale);
            sx[h[g0] + lr[j + 0]] = v.x;
            sx[h[g1] + lr[j + 1]] = v.y;
            sx[h[g2] + lr[j + 2]] = v.z;
            sx[h[g3] + lr[j + 3]] = v.w;
        }
    }
}

// ---- 4. wave-wide register bitonic sort of bucket-aligned windows ----
// bucket id is monotone in value, so within one segment a plain value sort of a
// bucket-aligned window reproduces the segmented sort; slot i pairs with y[W0+i].
template <int PL>
__device__ __forceinline__ void sort_diff(const float* __restrict__ sx,
                                          const float* __restrict__ y,
                                          int W0, int W1, int lane, float& acc) {
    float v[PL];
    #pragma unroll
    for (int r = 0; r < PL; ++r) {
        int idx = W0 + r * 64 + lane;
        v[r] = (idx < W1) ? sx[idx] : __builtin_inff();
    }
    const int n = PL * 64;
    #pragma unroll
    for (int k = 2; k <= n; k <<= 1) {
        #pragma unroll
        for (int j = k >> 1; j > 0; j >>= 1) {
            if (j >= 64) {                       // partner in another register plane
                int pj = j >> 6;
                #pragma unroll
                for (int r = 0; r < PL; ++r) {
                    if ((r & pj) == 0) {
                        int r2 = r | pj;
                        bool desc = ((r * 64) & k) != 0;   // k >= 128 here
                        float lo = fminf(v[r], v[r2]);
                        float hi = fmaxf(v[r], v[r2]);
                        v[r]  = desc ? hi : lo;
                        v[r2] = desc ? lo : hi;
                    }
                }
            } else {                             // partner in another lane
                bool amHigh = (lane & j) != 0;
                #pragma unroll
                for (int r = 0; r < PL; ++r) {
                    bool desc = (k >= 64) ? ((r & (k >> 6)) != 0) : ((lane & k) != 0);
                    float p = __shfl_xor(v[r], j, 64);
                    bool wantMax = amHigh != desc;
                    v[r] = wantMax ? fmaxf(v[r], p) : fminf(v[r], p);
                }
            }
        }
    }
    #pragma unroll
    for (int r = 0; r < PL; ++r) {
        int idx = W0 + r * 64 + lane;
        if (idx < W1) acc += fabsf(v[r] - y[idx]);
    }
}

__global__ void __launch_bounds__(256)
k_emd(const float* __restrict__ sx, const float* __restrict__ y,
      const int* __restrict__ E, const int* __restrict__ win_i,
      float* __restrict__ segSums, int N, int nwin) {
    int wid = blockIdx.x * 4 + (threadIdx.x >> 6);
    if (wid >= nwin) return;
    int lane = threadIdx.x & 63;
    int W0, gA;
    if (wid == 0) { W0 = 0; gA = 0; }
    else { int i0 = win_i[wid]; W0 = E[i0]; gA = i0 + 1; }
    int i1;
    if ((long)(wid + 1) * WIN > (long)N) i1 = M_TOT - 1;
    else i1 = win_i[wid + 1];
    int W1 = E[i1];
    int c = W1 - W0;
    if (c <= 0) return;
    int gB = i1;
    int sA = gA >> LOG_NB, sB = gB >> LOG_NB;
    if (sA == sB && c <= 256) {
        float acc = 0.f;
        if (c <= 64)       sort_diff<1>(sx, y, W0, W1, lane, acc);
        else if (c <= 128) sort_diff<2>(sx, y, W0, W1, lane, acc);
        else               sort_diff<4>(sx, y, W0, W1, lane, acc);
        for (int off = 32; off > 0; off >>= 1) acc += __shfl_xor(acc, off, 64);
        if (lane == 0) atomicAdd(&segSums[sB], acc);
    } else {
        // rare: segment-crossing window or oversized bucket -> exact rank scan
        for (int p = W0 + lane; p < W1; p += 64) {
            float v = sx[p];
            int lo = gA, hi = gB;
            while (lo < hi) { int mid = (lo + hi) >> 1; if (E[mid] > p) hi = mid; else lo = mid + 1; }
            int g = lo;
            int start = (g == 0) ? 0 : E[g - 1];
            int end = E[g];
            int rank = 0;
            for (int j = start; j < end; ++j) {
                float u = sx[j];
                rank += (u < v) || (u == v && j < p);
            }
            float d = fabsf(v - y[start + rank]);
            atomicAdd(&segSums[g >> LOG_NB], d);
        }
    }
}

// ---- 5. finalize ----
__global__ void k_final(const float* __restrict__ segSums, const int* __restrict__ seg_ends,
                        float* __restrict__ out) {
    __shared__ float red[256];
    int t = threadIdx.x;
    float acc = 0.f;
    for (int s = t; s < NSEG; s += 256) {
        int end = seg_ends[s];
        int st = (s == 0) ? 0 : seg_ends[s - 1];
        float cnt = (float)(end - st);
        acc += segSums[s] / fmaxf(cnt, 1.0f);
    }
    red[t] = acc;
    __syncthreads();
    for (int off = 128; off > 0; off >>= 1) {
        if (t < off) red[t] += red[t + off];
        __syncthreads();
    }
    if (t == 0) out[0] = red[0] * (1.0f / (float)NSEG) * STRENGTH;
}

extern "C" void kernel_launch(void* const* d_in, const int* in_sizes, int n_in,
                              void* d_out, int out_size, void* d_ws, size_t ws_size,
                              hipStream_t stream) {
    const float* x = (const float*)d_in[0];
    const float* y = (const float*)d_in[1];          // initial_sorted
    const int* seg = (const int*)d_in[2];            // segment_ids (sorted)
    int N = in_sizes[0];
    float scale = (float)NB / 12.0f;
    int nwin = (N + WIN - 1) / WIN;

    char* ws = (char*)d_ws;
    float* sx        = (float*)ws;                        // N floats
    int*   counts    = (int*)(ws + (size_t)N * 4);        // M_TOT ints
    int*   cursor    = counts + M_TOT;                    // M_TOT ints
    int*   partials  = cursor + M_TOT;                    // <=1024 ints
    float* segSums   = (float*)(partials + 1024);         // NSEG floats
    int*   seg_ends  = (int*)(segSums + NSEG);            // NSEG ints
    int*   seg_starts= seg_ends + NSEG;                   // NSEG+1 ints
    int*   win_i     = seg_starts + NSEG + 1;             // nwin+1 ints

    int nb = (M_TOT + 2047) / 2048;    // = 400
    int nchunk = (N + HCHUNK - 1) / HCHUNK;

    k_bounds<<<256, 256, 0, stream>>>(seg, seg_starts, counts, segSums, N);
    k_hist<<<nchunk, 512, 0, stream>>>(x, seg_starts, counts, N, scale);
    k_scan_partial<<<nb, 256, 0, stream>>>(counts, partials, M_TOT);
    k_scan_carry<<<1, 1024, 0, stream>>>(partials, nb);
    k_scan_final<<<nb, 256, 0, stream>>>(counts, partials, cursor, seg_ends, win_i, M_TOT);
    k_scatter<<<nchunk, 512, 0, stream>>>(x, seg_starts, cursor, sx, N, scale);
    k_emd<<<(nwin + 3) / 4, 256, 0, stream>>>(sx, y, cursor, win_i, segSums, N, nwin);
    k_final<<<1, 256, 0, stream>>>(segSums, seg_ends, (float*)d_out);
}

// Round 7
// 233.116 us; speedup vs baseline: 2.1259x; 2.1259x over previous
//
#include <hip/hip_runtime.h>
#include <hip/hip_bf16.h>
#include <limits.h>

#define NSEG 200
#define STRENGTH 1e-3f
#define NB 4096                 // coarse buckets per segment
#define LOG_NB 12
#define M_TOT (NSEG * NB)
#define HCH 16384               // elements per hist block
#define SCH 8192                // elements per scatter block
#define ECHUNK 2048             // elements per emd block
#define WCAP 2560               // LDS window capacity (ECHUNK + 2*max_bucket)
#define BCAP 2052               // staged bucket-ends capacity (span+2)

__device__ __forceinline__ int bucket_of(float x, float scale) {
    float t = (x + 6.0f) * scale;   // scale = NB/12
    int b = (int)floorf(t);
    b = b < 0 ? 0 : (b > NB - 1 ? NB - 1 : b);
    return b;
}

// ---- 0. segment boundaries from sorted seg ids + zero counts/segSums ----
__global__ void k_bounds(const int* __restrict__ seg, int* __restrict__ seg_starts,
                         int* __restrict__ counts, float* __restrict__ segSums, int N) {
    int stride = gridDim.x * blockDim.x;
    int tid = blockIdx.x * blockDim.x + threadIdx.x;
    for (int k = tid; k < M_TOT; k += stride) counts[k] = 0;
    for (int k = tid; k < NSEG; k += stride) segSums[k] = 0.f;
    if (tid == 0) { seg_starts[0] = 0; seg_starts[NSEG] = N; }
    const int4* s4 = (const int4*)seg;
    int N4 = N >> 2;
    for (int i = tid; i < N4; i += stride) {
        int4 s = s4[i];
        int prev = (i == 0) ? s.x : seg[i * 4 - 1];
        if (s.x != prev) seg_starts[s.x] = i * 4;
        if (s.y != s.x) seg_starts[s.y] = i * 4 + 1;
        if (s.z != s.y) seg_starts[s.z] = i * 4 + 2;
        if (s.w != s.z) seg_starts[s.w] = i * 4 + 3;
    }
}

// ---- 1. histogram of (segment, bucket) via per-block LDS hist ----
__global__ void __launch_bounds__(512)
k_hist(const float* __restrict__ x, const int* __restrict__ seg_starts,
       int* __restrict__ counts, int N, float scale) {
    __shared__ int h[2 * NB];
    __shared__ int sst[NSEG + 1];
    int t = threadIdx.x;
    for (int k = t; k < NSEG + 1; k += 512) sst[k] = seg_starts[k];
    for (int k = t; k < 2 * NB; k += 512) h[k] = 0;
    __syncthreads();
    int base = blockIdx.x * HCH;
    int lo = 0, hi = NSEG - 1;
    while (lo < hi) { int mid = (lo + hi) >> 1; if (base < sst[mid + 1]) hi = mid; else lo = mid + 1; }
    int s0 = lo, bnd = sst[lo + 1];
    const float4* x4 = (const float4*)x;
    for (int it = 0; it < HCH / (512 * 4); ++it) {
        int j = (it * 512 + t) * 4;
        int gi = base + j;
        if (gi < N) {
            float4 v = x4[(base >> 2) + it * 512 + t];
            int sel0 = (gi + 0) >= bnd ? NB : 0;
            int sel1 = (gi + 1) >= bnd ? NB : 0;
            int sel2 = (gi + 2) >= bnd ? NB : 0;
            int sel3 = (gi + 3) >= bnd ? NB : 0;
            atomicAdd(&h[sel0 + bucket_of(v.x, scale)], 1);
            atomicAdd(&h[sel1 + bucket_of(v.y, scale)], 1);
            atomicAdd(&h[sel2 + bucket_of(v.z, scale)], 1);
            atomicAdd(&h[sel3 + bucket_of(v.w, scale)], 1);
        }
    }
    __syncthreads();
    for (int k = t; k < 2 * NB; k += 512) {
        int c = h[k];
        if (c > 0) atomicAdd(&counts[(s0 + (k >= NB)) * NB + (k & (NB - 1))], c);
    }
}

// ---- 2. exclusive scan over M_TOT counters ----
__global__ void k_scan_partial(const int* __restrict__ counts, int* __restrict__ partials, int M) {
    __shared__ int sdata[256];
    int base = blockIdx.x * 2048;
    int sum = 0;
    for (int k = threadIdx.x; k < 2048; k += 256) {
        int idx = base + k;
        sum += (idx < M) ? counts[idx] : 0;
    }
    sdata[threadIdx.x] = sum;
    __syncthreads();
    for (int off = 128; off > 0; off >>= 1) {
        if (threadIdx.x < off) sdata[threadIdx.x] += sdata[threadIdx.x + off];
        __syncthreads();
    }
    if (threadIdx.x == 0) partials[blockIdx.x] = sdata[0];
}

__global__ void k_scan_carry(int* __restrict__ partials, int nb) {
    __shared__ int bufA[1024], bufB[1024];
    int t = threadIdx.x;
    int v = (t < nb) ? partials[t] : 0;
    int* src = bufA; int* dst = bufB;
    src[t] = v;
    __syncthreads();
    for (int off = 1; off < 1024; off <<= 1) {
        dst[t] = src[t] + ((t >= off) ? src[t - off] : 0);
        __syncthreads();
        int* tmp = src; src = dst; dst = tmp;
    }
    if (t < nb) partials[t] = src[t] - v;   // exclusive
}

__global__ void k_scan_final(const int* __restrict__ counts, const int* __restrict__ partials,
                             int* __restrict__ cursor, int* __restrict__ seg_ends, int M) {
    __shared__ int tile[2048];
    __shared__ int sa[256], sb[256];
    int t = threadIdx.x;
    int base = blockIdx.x * 2048;
    for (int k = t; k < 2048; k += 256) {
        int idx = base + k;
        tile[k] = (idx < M) ? counts[idx] : 0;
    }
    __syncthreads();
    int loc[8]; int run = 0;
    for (int k = 0; k < 8; ++k) { loc[k] = run; run += tile[t * 8 + k]; }
    int v = run;
    int* src = sa; int* dst = sb;
    __syncthreads();
    src[t] = v;
    __syncthreads();
    for (int off = 1; off < 256; off <<= 1) {
        int w = src[t] + ((t >= off) ? src[t - off] : 0);
        dst[t] = w;
        __syncthreads();
        int* tmp = src; src = dst; dst = tmp;
    }
    int texcl = src[t] - v;
    int gbase = partials[blockIdx.x];
    for (int k = 0; k < 8; ++k) {
        int idx = base + t * 8 + k;
        if (idx < M) {
            int excl = gbase + texcl + loc[k];
            cursor[idx] = excl;
            if (((idx + 1) & (NB - 1)) == 0)
                seg_ends[((idx + 1) >> LOG_NB) - 1] = excl + tile[t * 8 + k];
        }
    }
}

// ---- 3. scatter with per-block reservation (cursor: starts -> ends) ----
__global__ void __launch_bounds__(512)
k_scatter(const float* __restrict__ x, const int* __restrict__ seg_starts,
          int* __restrict__ cursor, float* __restrict__ sx, int N, float scale) {
    __shared__ int h[2 * NB];
    __shared__ unsigned short lr[SCH];
    __shared__ int sst[NSEG + 1];
    int t = threadIdx.x;
    for (int k = t; k < NSEG + 1; k += 512) sst[k] = seg_starts[k];
    for (int k = t; k < 2 * NB; k += 512) h[k] = 0;
    __syncthreads();
    int base = blockIdx.x * SCH;
    int lo = 0, hi = NSEG - 1;
    while (lo < hi) { int mid = (lo + hi) >> 1; if (base < sst[mid + 1]) hi = mid; else lo = mid + 1; }
    int s0 = lo, bnd = sst[lo + 1];
    const float4* x4 = (const float4*)x;
    // pass 1: local ranks
    for (int it = 0; it < SCH / (512 * 4); ++it) {
        int j = (it * 512 + t) * 4;
        int gi = base + j;
        if (gi < N) {
            float4 v = x4[(base >> 2) + it * 512 + t];
            int g0 = ((gi + 0) >= bnd ? NB : 0) + bucket_of(v.x, scale);
            int g1 = ((gi + 1) >= bnd ? NB : 0) + bucket_of(v.y, scale);
            int g2 = ((gi + 2) >= bnd ? NB : 0) + bucket_of(v.z, scale);
            int g3 = ((gi + 3) >= bnd ? NB : 0) + bucket_of(v.w, scale);
            lr[j + 0] = (unsigned short)atomicAdd(&h[g0], 1);
            lr[j + 1] = (unsigned short)atomicAdd(&h[g1], 1);
            lr[j + 2] = (unsigned short)atomicAdd(&h[g2], 1);
            lr[j + 3] = (unsigned short)atomicAdd(&h[g3], 1);
        }
    }
    __syncthreads();
    // reserve: h[k] becomes global base for this block's (seg,bucket) group
    for (int k = t; k < 2 * NB; k += 512) {
        int c = h[k];
        if (c > 0) h[k] = atomicAdd(&cursor[(s0 + (k >= NB)) * NB + (k & (NB - 1))], c);
    }
    __syncthreads();
    // pass 2: write
    for (int it = 0; it < SCH / (512 * 4); ++it) {
        int j = (it * 512 + t) * 4;
        int gi = base + j;
        if (gi < N) {
            float4 v = x4[(base >> 2) + it * 512 + t];
            int g0 = ((gi + 0) >= bnd ? NB : 0) + bucket_of(v.x, scale);
            int g1 = ((gi + 1) >= bnd ? NB : 0) + bucket_of(v.y, scale);
            int g2 = ((gi + 2) >= bnd ? NB : 0) + bucket_of(v.z, scale);
            int g3 = ((gi + 3) >= bnd ? NB : 0) + bucket_of(v.w, scale);
            sx[h[g0] + lr[j + 0]] = v.x;
            sx[h[g1] + lr[j + 1]] = v.y;
            sx[h[g2] + lr[j + 2]] = v.z;
            sx[h[g3] + lr[j + 3]] = v.w;
        }
    }
}

// ---- 4. rank within bucket via LDS window; y gathered (L1-resident window) ----
__global__ void __launch_bounds__(256)
k_emd(const float* __restrict__ sx, const float* __restrict__ y,
      const int* __restrict__ ends, const int* __restrict__ seg_ends,
      float* __restrict__ segSums, int N, float scale) {
    __shared__ float win[WCAP];
    __shared__ int bends[BCAP];
    __shared__ int sEnd[NSEG];
    __shared__ int sh[5];
    int tid = threadIdx.x;
    for (int k = tid; k < NSEG; k += 256) sEnd[k] = seg_ends[k];
    __syncthreads();
    int pbase = blockIdx.x * ECHUNK;
    int pend = min(pbase + ECHUNK, N);
    if (tid == 0) {
        float v = sx[pbase];
        int lo = 0, hi = NSEG - 1;
        while (lo < hi) { int mid = (lo + hi) >> 1; if (pbase < sEnd[mid]) hi = mid; else lo = mid + 1; }
        int g = lo * NB + bucket_of(v, scale);
        sh[0] = (g == 0) ? 0 : ends[g - 1];
        sh[2] = lo;
        sh[3] = g;
    }
    if (tid == 255) {
        float v = sx[pend - 1];
        int lo = 0, hi = NSEG - 1;
        while (lo < hi) { int mid = (lo + hi) >> 1; if (pend - 1 < sEnd[mid]) hi = mid; else lo = mid + 1; }
        int g = lo * NB + bucket_of(v, scale);
        sh[1] = ends[g];
        sh[4] = g;
    }
    __syncthreads();
    int wlo = sh[0], whi = sh[1], s0 = sh[2], gfirst = sh[3], glast = sh[4];
    int wsz = whi - wlo;
    bool fits = wsz <= WCAP;
    int bcount = glast - gfirst + 2;
    bool useB = fits && bcount <= BCAP;
    bool cross = (glast >> LOG_NB) != s0;
    if (fits) {
        for (int k = tid; k < wsz; k += 256) win[k] = sx[wlo + k];
    }
    if (useB) {
        for (int k = tid; k < bcount; k += 256) {
            int g = gfirst - 1 + k;
            bends[k] = (g < 0) ? 0 : ends[g];
        }
    }
    __syncthreads();

    float acc0 = 0.f, acc1 = 0.f;
    if (useB && !cross) {
        // fast path: single segment, staged bucket-ends, staged window
        #pragma unroll
        for (int e = 0; e < ECHUNK / 256; ++e) {
            int p = pbase + (e << 8) + tid;
            if (p >= pend) break;
            int widx = p - wlo;
            float v = win[widx];
            int bi = bucket_of(v, scale) + s0 * NB - gfirst;
            int start = bends[bi];
            int a = start - wlo, bq = bends[bi + 1] - wlo;
            int rank = 0;
            int k = a;
            for (; k < bq && (k & 3); ++k) { float vj = win[k]; rank += (vj < v) || (vj == v && k < widx); }
            for (; k + 3 < bq; k += 4) {
                float4 q = *(const float4*)&win[k];
                rank += (q.x < v) || (q.x == v && (k)     < widx);
                rank += (q.y < v) || (q.y == v && (k + 1) < widx);
                rank += (q.z < v) || (q.z == v && (k + 2) < widx);
                rank += (q.w < v) || (q.w == v && (k + 3) < widx);
            }
            for (; k < bq; ++k) { float vj = win[k]; rank += (vj < v) || (vj == v && k < widx); }
            acc0 += fabsf(v - y[start + rank]);
        }
    } else if (fits) {
        // medium path: segment-crossing or wide-span window; global bucket-ends
        for (int e = 0; e < ECHUNK / 256; ++e) {
            int p = pbase + (e << 8) + tid;
            if (p >= pend) break;
            int s = s0;
            while (p >= sEnd[s]) ++s;
            int widx = p - wlo;
            float v = win[widx];
            int g = s * NB + bucket_of(v, scale);
            int start = (g == 0) ? 0 : ends[g - 1];
            int end = ends[g];
            int a = start - wlo, bq = end - wlo;
            int rank = 0;
            int k = a;
            for (; k < bq && (k & 3); ++k) { float vj = win[k]; rank += (vj < v) || (vj == v && k < widx); }
            for (; k + 3 < bq; k += 4) {
                float4 q = *(const float4*)&win[k];
                rank += (q.x < v) || (q.x == v && (k)     < widx);
                rank += (q.y < v) || (q.y == v && (k + 1) < widx);
                rank += (q.z < v) || (q.z == v && (k + 2) < widx);
                rank += (q.w < v) || (q.w == v && (k + 3) < widx);
            }
            for (; k < bq; ++k) { float vj = win[k]; rank += (vj < v) || (vj == v && k < widx); }
            float diff = fabsf(v - y[start + rank]);
            if (s == s0) acc0 += diff;
            else if (s == s0 + 1) acc1 += diff;
            else atomicAdd(&segSums[s], diff);
        }
    } else {
        // global fallback (window exceeds LDS — should not happen at these sizes)
        for (int e = 0; e < ECHUNK / 256; ++e) {
            int p = pbase + (e << 8) + tid;
            if (p >= pend) break;
            int s = s0;
            while (p >= sEnd[s]) ++s;
            float v = sx[p];
            int g = s * NB + bucket_of(v, scale);
            int start = (g == 0) ? 0 : ends[g - 1];
            int end = ends[g];
            int rank = 0;
            for (int j = start; j < end; ++j) { float vj = sx[j]; rank += (vj < v) || (vj == v && j < p); }
            float diff = fabsf(v - y[start + rank]);
            if (s == s0) acc0 += diff;
            else if (s == s0 + 1) acc1 += diff;
            else atomicAdd(&segSums[s], diff);
        }
    }

    for (int off = 32; off > 0; off >>= 1) {
        acc0 += __shfl_xor(acc0, off);
        acc1 += __shfl_xor(acc1, off);
    }
    if ((tid & 63) == 0) {
        if (acc0 != 0.f) atomicAdd(&segSums[s0], acc0);
        if (acc1 != 0.f && s0 + 1 < NSEG) atomicAdd(&segSums[s0 + 1], acc1);
    }
}

// ---- 5. finalize ----
__global__ void k_final(const float* __restrict__ segSums, const int* __restrict__ seg_ends,
                        float* __restrict__ out) {
    __shared__ float red[256];
    int t = threadIdx.x;
    float acc = 0.f;
    for (int s = t; s < NSEG; s += 256) {
        int end = seg_ends[s];
        int st = (s == 0) ? 0 : seg_ends[s - 1];
        float cnt = (float)(end - st);
        acc += segSums[s] / fmaxf(cnt, 1.0f);
    }
    red[t] = acc;
    __syncthreads();
    for (int off = 128; off > 0; off >>= 1) {
        if (t < off) red[t] += red[t + off];
        __syncthreads();
    }
    if (t == 0) out[0] = red[0] * (1.0f / (float)NSEG) * STRENGTH;
}

extern "C" void kernel_launch(void* const* d_in, const int* in_sizes, int n_in,
                              void* d_out, int out_size, void* d_ws, size_t ws_size,
                              hipStream_t stream) {
    const float* x = (const float*)d_in[0];
    const float* y = (const float*)d_in[1];          // initial_sorted
    const int* seg = (const int*)d_in[2];            // segment_ids (sorted)
    int N = in_sizes[0];
    float scale = (float)NB / 12.0f;

    char* ws = (char*)d_ws;
    float* sx        = (float*)ws;                        // N floats
    int*   counts    = (int*)(ws + (size_t)N * 4);        // M_TOT ints
    int*   cursor    = counts + M_TOT;                    // M_TOT ints
    int*   partials  = cursor + M_TOT;                    // <=1024 ints
    float* segSums   = (float*)(partials + 1024);         // NSEG floats
    int*   seg_ends  = (int*)(segSums + NSEG);            // NSEG ints
    int*   seg_starts= seg_ends + NSEG;                   // NSEG+1 ints

    int nb = (M_TOT + 2047) / 2048;    // = 400
    int nch_h = (N + HCH - 1) / HCH;   // 512
    int nch_s = (N + SCH - 1) / SCH;   // 1024

    k_bounds<<<512, 256, 0, stream>>>(seg, seg_starts, counts, segSums, N);
    k_hist<<<nch_h, 512, 0, stream>>>(x, seg_starts, counts, N, scale);
    k_scan_partial<<<nb, 256, 0, stream>>>(counts, partials, M_TOT);
    k_scan_carry<<<1, 1024, 0, stream>>>(partials, nb);
    k_scan_final<<<nb, 256, 0, stream>>>(counts, partials, cursor, seg_ends, M_TOT);
    k_scatter<<<nch_s, 512, 0, stream>>>(x, seg_starts, cursor, sx, N, scale);
    k_emd<<<(N + ECHUNK - 1) / ECHUNK, 256, 0, stream>>>(sx, y, cursor, seg_ends, segSums, N, scale);
    k_final<<<1, 256, 0, stream>>>(segSums, seg_ends, (float*)d_out);
}

// Round 9
// 231.677 us; speedup vs baseline: 2.1391x; 1.0062x over previous
//
#include <hip/hip_runtime.h>
#include <hip/hip_bf16.h>
#include <limits.h>

#define NSEG 200
#define STRENGTH 1e-3f
#define NB 4096                 // coarse buckets per segment
#define LOG_NB 12
#define M_TOT (NSEG * NB)
#define HCH 16384               // elements per hist block
#define SCH 8192                // elements per scatter block
#define ECHUNK 2048             // elements per emd block
#define WCAP 2560               // LDS window capacity (ECHUNK + 2*max_bucket)
#define BCAP 2052               // staged bucket-ends capacity (span+2)

__device__ __forceinline__ int bucket_of(float x, float scale) {
    float t = (x + 6.0f) * scale;   // scale = NB/12
    int b = (int)floorf(t);
    b = b < 0 ? 0 : (b > NB - 1 ? NB - 1 : b);
    return b;
}

// ---- 0. segment boundaries from sorted seg ids + zero counts/segSums ----
__global__ void k_bounds(const int* __restrict__ seg, int* __restrict__ seg_starts,
                         int* __restrict__ counts, float* __restrict__ segSums, int N) {
    int stride = gridDim.x * blockDim.x;
    int tid = blockIdx.x * blockDim.x + threadIdx.x;
    for (int k = tid; k < M_TOT; k += stride) counts[k] = 0;
    for (int k = tid; k < NSEG; k += stride) segSums[k] = 0.f;
    if (tid == 0) { seg_starts[0] = 0; seg_starts[NSEG] = N; }
    const int4* s4 = (const int4*)seg;
    int N4 = N >> 2;
    for (int i = tid; i < N4; i += stride) {
        int4 s = s4[i];
        int prev = (i == 0) ? s.x : seg[i * 4 - 1];
        if (s.x != prev) seg_starts[s.x] = i * 4;
        if (s.y != s.x) seg_starts[s.y] = i * 4 + 1;
        if (s.z != s.y) seg_starts[s.z] = i * 4 + 2;
        if (s.w != s.z) seg_starts[s.w] = i * 4 + 3;
    }
}

// ---- 1. histogram of (segment, bucket) via per-block LDS hist ----
__global__ void __launch_bounds__(512)
k_hist(const float* __restrict__ x, const int* __restrict__ seg_starts,
       int* __restrict__ counts, int N, float scale) {
    __shared__ int h[2 * NB];
    __shared__ int sst[NSEG + 1];
    int t = threadIdx.x;
    for (int k = t; k < NSEG + 1; k += 512) sst[k] = seg_starts[k];
    for (int k = t; k < 2 * NB; k += 512) h[k] = 0;
    __syncthreads();
    int base = blockIdx.x * HCH;
    int lo = 0, hi = NSEG - 1;
    while (lo < hi) { int mid = (lo + hi) >> 1; if (base < sst[mid + 1]) hi = mid; else lo = mid + 1; }
    int s0 = lo, bnd = sst[lo + 1];
    const float4* x4 = (const float4*)x;
    for (int it = 0; it < HCH / (512 * 4); ++it) {
        int j = (it * 512 + t) * 4;
        int gi = base + j;
        if (gi < N) {
            float4 v = x4[(base >> 2) + it * 512 + t];
            int sel0 = (gi + 0) >= bnd ? NB : 0;
            int sel1 = (gi + 1) >= bnd ? NB : 0;
            int sel2 = (gi + 2) >= bnd ? NB : 0;
            int sel3 = (gi + 3) >= bnd ? NB : 0;
            atomicAdd(&h[sel0 + bucket_of(v.x, scale)], 1);
            atomicAdd(&h[sel1 + bucket_of(v.y, scale)], 1);
            atomicAdd(&h[sel2 + bucket_of(v.z, scale)], 1);
            atomicAdd(&h[sel3 + bucket_of(v.w, scale)], 1);
        }
    }
    __syncthreads();
    for (int k = t; k < 2 * NB; k += 512) {
        int c = h[k];
        if (c > 0) atomicAdd(&counts[(s0 + (k >= NB)) * NB + (k & (NB - 1))], c);
    }
}

// ---- 2. scan over M_TOT counters (partial sums, then final with inline carry) ----
__global__ void k_scan_partial(const int* __restrict__ counts, int* __restrict__ partials, int M) {
    __shared__ int sdata[256];
    int base = blockIdx.x * 2048;
    int sum = 0;
    for (int k = threadIdx.x; k < 2048; k += 256) {
        int idx = base + k;
        sum += (idx < M) ? counts[idx] : 0;
    }
    sdata[threadIdx.x] = sum;
    __syncthreads();
    for (int off = 128; off > 0; off >>= 1) {
        if (threadIdx.x < off) sdata[threadIdx.x] += sdata[threadIdx.x + off];
        __syncthreads();
    }
    if (threadIdx.x == 0) partials[blockIdx.x] = sdata[0];
}

__global__ void k_scan_final(const int* __restrict__ counts, const int* __restrict__ partials,
                             int* __restrict__ cursor, int* __restrict__ seg_ends, int M) {
    __shared__ int tile[2048];
    __shared__ int sa[256], sb[256];
    int t = threadIdx.x;
    int base = blockIdx.x * 2048;
    // inline carry: exclusive sum of partials[0..blockIdx.x)
    int c = 0;
    for (int k = t; k < blockIdx.x; k += 256) c += partials[k];
    sa[t] = c;
    __syncthreads();
    for (int off = 128; off > 0; off >>= 1) {
        if (t < off) sa[t] += sa[t + off];
        __syncthreads();
    }
    int gbase = sa[0];
    __syncthreads();
    for (int k = t; k < 2048; k += 256) {
        int idx = base + k;
        tile[k] = (idx < M) ? counts[idx] : 0;
    }
    __syncthreads();
    int loc[8]; int run = 0;
    for (int k = 0; k < 8; ++k) { loc[k] = run; run += tile[t * 8 + k]; }
    int v = run;
    int* src = sa; int* dst = sb;
    src[t] = v;
    __syncthreads();
    for (int off = 1; off < 256; off <<= 1) {
        int w = src[t] + ((t >= off) ? src[t - off] : 0);
        dst[t] = w;
        __syncthreads();
        int* tmp = src; src = dst; dst = tmp;
    }
    int texcl = src[t] - v;
    for (int k = 0; k < 8; ++k) {
        int idx = base + t * 8 + k;
        if (idx < M) {
            int excl = gbase + texcl + loc[k];
            cursor[idx] = excl;
            if (((idx + 1) & (NB - 1)) == 0)
                seg_ends[((idx + 1) >> LOG_NB) - 1] = excl + tile[t * 8 + k];
        }
    }
}

// ---- 3. scatter with per-block reservation (cursor: starts -> ends) ----
__global__ void __launch_bounds__(512)
k_scatter(const float* __restrict__ x, const int* __restrict__ seg_starts,
          int* __restrict__ cursor, float* __restrict__ sx, int N, float scale) {
    __shared__ int h[2 * NB];
    __shared__ unsigned short lr[SCH];
    __shared__ int sst[NSEG + 1];
    int t = threadIdx.x;
    for (int k = t; k < NSEG + 1; k += 512) sst[k] = seg_starts[k];
    for (int k = t; k < 2 * NB; k += 512) h[k] = 0;
    __syncthreads();
    int base = blockIdx.x * SCH;
    int lo = 0, hi = NSEG - 1;
    while (lo < hi) { int mid = (lo + hi) >> 1; if (base < sst[mid + 1]) hi = mid; else lo = mid + 1; }
    int s0 = lo, bnd = sst[lo + 1];
    const float4* x4 = (const float4*)x;
    // pass 1: local ranks
    for (int it = 0; it < SCH / (512 * 4); ++it) {
        int j = (it * 512 + t) * 4;
        int gi = base + j;
        if (gi < N) {
            float4 v = x4[(base >> 2) + it * 512 + t];
            int g0 = ((gi + 0) >= bnd ? NB : 0) + bucket_of(v.x, scale);
            int g1 = ((gi + 1) >= bnd ? NB : 0) + bucket_of(v.y, scale);
            int g2 = ((gi + 2) >= bnd ? NB : 0) + bucket_of(v.z, scale);
            int g3 = ((gi + 3) >= bnd ? NB : 0) + bucket_of(v.w, scale);
            lr[j + 0] = (unsigned short)atomicAdd(&h[g0], 1);
            lr[j + 1] = (unsigned short)atomicAdd(&h[g1], 1);
            lr[j + 2] = (unsigned short)atomicAdd(&h[g2], 1);
            lr[j + 3] = (unsigned short)atomicAdd(&h[g3], 1);
        }
    }
    __syncthreads();
    // reserve: h[k] becomes global base for this block's (seg,bucket) group
    for (int k = t; k < 2 * NB; k += 512) {
        int c = h[k];
        if (c > 0) h[k] = atomicAdd(&cursor[(s0 + (k >= NB)) * NB + (k & (NB - 1))], c);
    }
    __syncthreads();
    // pass 2: write
    for (int it = 0; it < SCH / (512 * 4); ++it) {
        int j = (it * 512 + t) * 4;
        int gi = base + j;
        if (gi < N) {
            float4 v = x4[(base >> 2) + it * 512 + t];
            int g0 = ((gi + 0) >= bnd ? NB : 0) + bucket_of(v.x, scale);
            int g1 = ((gi + 1) >= bnd ? NB : 0) + bucket_of(v.y, scale);
            int g2 = ((gi + 2) >= bnd ? NB : 0) + bucket_of(v.z, scale);
            int g3 = ((gi + 3) >= bnd ? NB : 0) + bucket_of(v.w, scale);
            sx[h[g0] + lr[j + 0]] = v.x;
            sx[h[g1] + lr[j + 1]] = v.y;
            sx[h[g2] + lr[j + 2]] = v.z;
            sx[h[g3] + lr[j + 3]] = v.w;
        }
    }
}

// ---- 4. rank within bucket via LDS window; batched ILP fast path ----
__global__ void __launch_bounds__(256)
k_emd(const float* __restrict__ sx, const float* __restrict__ y,
      const int* __restrict__ ends, const int* __restrict__ seg_ends,
      float* __restrict__ segSums, int N, float scale) {
    __shared__ float win[WCAP + 8];
    __shared__ int bends[BCAP];
    __shared__ int sEnd[NSEG];
    __shared__ int sh[5];
    int tid = threadIdx.x;
    for (int k = tid; k < NSEG; k += 256) sEnd[k] = seg_ends[k];
    __syncthreads();
    int pbase = blockIdx.x * ECHUNK;
    int pend = min(pbase + ECHUNK, N);
    if (tid == 0) {
        float v = sx[pbase];
        int lo = 0, hi = NSEG - 1;
        while (lo < hi) { int mid = (lo + hi) >> 1; if (pbase < sEnd[mid]) hi = mid; else lo = mid + 1; }
        int g = lo * NB + bucket_of(v, scale);
        sh[0] = (g == 0) ? 0 : ends[g - 1];
        sh[2] = lo;
        sh[3] = g;
    }
    if (tid == 255) {
        float v = sx[pend - 1];
        int lo = 0, hi = NSEG - 1;
        while (lo < hi) { int mid = (lo + hi) >> 1; if (pend - 1 < sEnd[mid]) hi = mid; else lo = mid + 1; }
        int g = lo * NB + bucket_of(v, scale);
        sh[1] = ends[g];
        sh[4] = g;
    }
    __syncthreads();
    int wlo = sh[0], whi = sh[1], s0 = sh[2], gfirst = sh[3], glast = sh[4];
    int wsz = whi - wlo;
    bool fits = wsz <= WCAP;
    int bcount = glast - gfirst + 2;
    bool useB = fits && bcount <= BCAP;
    bool cross = (glast >> LOG_NB) != s0;
    bool full = (pend - pbase) == ECHUNK;
    if (fits) {
        for (int k = tid; k < wsz; k += 256) win[k] = sx[wlo + k];
        if (tid < 8) win[wsz + tid] = __builtin_inff();   // pad for 8-wide over-read
    }
    if (useB) {
        for (int k = tid; k < bcount; k += 256) {
            int g = gfirst - 1 + k;
            bends[k] = (g < 0) ? 0 : ends[g];
        }
    }
    __syncthreads();

    float acc0 = 0.f, acc1 = 0.f;
    if (useB && !cross && full) {
        // fast path: single segment, full block; batched for ILP.
        // Window is provably single-segment here, so: pre-read [a&~3,a) hits
        // strictly-smaller earlier buckets (cancelled by rank init) and
        // over-read past b hits strictly-larger later buckets / INF pad.
        int base_w = pbase - wlo;
        int boff = s0 * NB - gfirst;
        float v[8]; int st[8]; int bq[8]; int idx[8];
        #pragma unroll
        for (int e = 0; e < 8; ++e) v[e] = win[base_w + (e << 8) + tid];
        #pragma unroll
        for (int e = 0; e < 8; ++e) {
            int bi = bucket_of(v[e], scale) + boff;
            st[e] = bends[bi];
            bq[e] = bends[bi + 1] - wlo;
        }
        #pragma unroll
        for (int e = 0; e < 8; ++e) {
            int widx = base_w + (e << 8) + tid;
            float vv = v[e];
            int a = st[e] - wlo;
            int k = a & ~3;
            int rank = k - a;             // elements in [k,a) are strictly smaller
            int b = bq[e];
            for (; k < b; k += 8) {
                float4 q0 = *(const float4*)&win[k];
                float4 q1 = *(const float4*)&win[k + 4];
                rank += (q0.x < vv) + ((q0.x == vv) & (k + 0 < widx));
                rank += (q0.y < vv) + ((q0.y == vv) & (k + 1 < widx));
                rank += (q0.z < vv) + ((q0.z == vv) & (k + 2 < widx));
                rank += (q0.w < vv) + ((q0.w == vv) & (k + 3 < widx));
                rank += (q1.x < vv) + ((q1.x == vv) & (k + 4 < widx));
                rank += (q1.y < vv) + ((q1.y == vv) & (k + 5 < widx));
                rank += (q1.z < vv) + ((q1.z == vv) & (k + 6 < widx));
                rank += (q1.w < vv) + ((q1.w == vv) & (k + 7 < widx));
            }
            idx[e] = st[e] + rank;
        }
        #pragma unroll
        for (int e = 0; e < 8; ++e) acc0 += fabsf(v[e] - y[idx[e]]);
    } else if (fits) {
        // medium path: segment-crossing / wide-span / partial block.
        // MUST NOT read outside [a, bqq): neighbors may belong to another
        // segment (not value-ordered relative to v). Checked prologue + exact tail.
        for (int e = 0; e < ECHUNK / 256; ++e) {
            int p = pbase + (e << 8) + tid;
            if (p >= pend) break;
            int s = s0;
            while (p >= sEnd[s]) ++s;
            int widx = p - wlo;
            float v = win[widx];
            int g = s * NB + bucket_of(v, scale);
            int start, end;
            if (useB) { start = bends[g - gfirst]; end = bends[g - gfirst + 1]; }
            else { start = (g == 0) ? 0 : ends[g - 1]; end = ends[g]; }
            int a = start - wlo, bqq = end - wlo;
            int rank = 0;
            int k = a;
            for (; k < bqq && (k & 3); ++k) { float vj = win[k]; rank += (vj < v) + ((vj == v) & (k < widx)); }
            for (; k + 3 < bqq; k += 4) {
                float4 q = *(const float4*)&win[k];
                rank += (q.x < v) + ((q.x == v) & (k + 0 < widx));
                rank += (q.y < v) + ((q.y == v) & (k + 1 < widx));
                rank += (q.z < v) + ((q.z == v) & (k + 2 < widx));
                rank += (q.w < v) + ((q.w == v) & (k + 3 < widx));
            }
            for (; k < bqq; ++k) { float vj = win[k]; rank += (vj < v) + ((vj == v) & (k < widx)); }
            float diff = fabsf(v - y[start + rank]);
            if (s == s0) acc0 += diff;
            else if (s == s0 + 1) acc1 += diff;
            else atomicAdd(&segSums[s], diff);
        }
    } else {
        // global fallback (window exceeds LDS — should not happen at these sizes)
        for (int e = 0; e < ECHUNK / 256; ++e) {
            int p = pbase + (e << 8) + tid;
            if (p >= pend) break;
            int s = s0;
            while (p >= sEnd[s]) ++s;
            float v = sx[p];
            int g = s * NB + bucket_of(v, scale);
            int start = (g == 0) ? 0 : ends[g - 1];
            int end = ends[g];
            int rank = 0;
            for (int j = start; j < end; ++j) { float vj = sx[j]; rank += (vj < v) || (vj == v && j < p); }
            float diff = fabsf(v - y[start + rank]);
            if (s == s0) acc0 += diff;
            else if (s == s0 + 1) acc1 += diff;
            else atomicAdd(&segSums[s], diff);
        }
    }

    for (int off = 32; off > 0; off >>= 1) {
        acc0 += __shfl_xor(acc0, off);
        acc1 += __shfl_xor(acc1, off);
    }
    if ((tid & 63) == 0) {
        if (acc0 != 0.f) atomicAdd(&segSums[s0], acc0);
        if (acc1 != 0.f && s0 + 1 < NSEG) atomicAdd(&segSums[s0 + 1], acc1);
    }
}

// ---- 5. finalize ----
__global__ void k_final(const float* __restrict__ segSums, const int* __restrict__ seg_ends,
                        float* __restrict__ out) {
    __shared__ float red[256];
    int t = threadIdx.x;
    float acc = 0.f;
    for (int s = t; s < NSEG; s += 256) {
        int end = seg_ends[s];
        int st = (s == 0) ? 0 : seg_ends[s - 1];
        float cnt = (float)(end - st);
        acc += segSums[s] / fmaxf(cnt, 1.0f);
    }
    red[t] = acc;
    __syncthreads();
    for (int off = 128; off > 0; off >>= 1) {
        if (t < off) red[t] += red[t + off];
        __syncthreads();
    }
    if (t == 0) out[0] = red[0] * (1.0f / (float)NSEG) * STRENGTH;
}

extern "C" void kernel_launch(void* const* d_in, const int* in_sizes, int n_in,
                              void* d_out, int out_size, void* d_ws, size_t ws_size,
                              hipStream_t stream) {
    const float* x = (const float*)d_in[0];
    const float* y = (const float*)d_in[1];          // initial_sorted
    const int* seg = (const int*)d_in[2];            // segment_ids (sorted)
    int N = in_sizes[0];
    float scale = (float)NB / 12.0f;

    char* ws = (char*)d_ws;
    float* sx        = (float*)ws;                        // N floats
    int*   counts    = (int*)(ws + (size_t)N * 4);        // M_TOT ints
    int*   cursor    = counts + M_TOT;                    // M_TOT ints
    int*   partials  = cursor + M_TOT;                    // <=1024 ints
    float* segSums   = (float*)(partials + 1024);         // NSEG floats
    int*   seg_ends  = (int*)(segSums + NSEG);            // NSEG ints
    int*   seg_starts= seg_ends + NSEG;                   // NSEG+1 ints

    int nb = (M_TOT + 2047) / 2048;    // = 400
    int nch_h = (N + HCH - 1) / HCH;
    int nch_s = (N + SCH - 1) / SCH;

    k_bounds<<<512, 256, 0, stream>>>(seg, seg_starts, counts, segSums, N);
    k_hist<<<nch_h, 512, 0, stream>>>(x, seg_starts, counts, N, scale);
    k_scan_partial<<<nb, 256, 0, stream>>>(counts, partials, M_TOT);
    k_scan_final<<<nb, 256, 0, stream>>>(counts, partials, cursor, seg_ends, M_TOT);
    k_scatter<<<nch_s, 512, 0, stream>>>(x, seg_starts, cursor, sx, N, scale);
    k_emd<<<(N + ECHUNK - 1) / ECHUNK, 256, 0, stream>>>(sx, y, cursor, seg_ends, segSums, N, scale);
    k_final<<<1, 256, 0, stream>>>(segSums, seg_ends, (float*)d_out);
}

// Round 10
// 227.405 us; speedup vs baseline: 2.1793x; 1.0188x over previous
//
#include <hip/hip_runtime.h>
#include <hip/hip_bf16.h>
#include <limits.h>

#define NSEG 200
#define STRENGTH 1e-3f
#define NB 4096                 // coarse buckets per segment
#define LOG_NB 12
#define M_TOT (NSEG * NB)
#define HCH 16384               // elements per hist block
#define SCH 8192                // elements per scatter block
#define ECHUNK 2048             // elements per emd block
#define WCAP 2560               // window capacity (ECHUNK + 2*max_bucket)
#define BCAP 2052               // fallback staged bucket-ends capacity
#define SPAN_S 256              // sorted-path max bucket span

__device__ __forceinline__ int bucket_of(float x, float scale) {
    float t = (x + 6.0f) * scale;   // scale = NB/12
    int b = (int)floorf(t);
    b = b < 0 ? 0 : (b > NB - 1 ? NB - 1 : b);
    return b;
}

// ---- 0. segment boundaries from sorted seg ids + zero counts/segSums ----
__global__ void k_bounds(const int* __restrict__ seg, int* __restrict__ seg_starts,
                         int* __restrict__ counts, float* __restrict__ segSums, int N) {
    int stride = gridDim.x * blockDim.x;
    int tid = blockIdx.x * blockDim.x + threadIdx.x;
    for (int k = tid; k < M_TOT; k += stride) counts[k] = 0;
    for (int k = tid; k < NSEG; k += stride) segSums[k] = 0.f;
    if (tid == 0) { seg_starts[0] = 0; seg_starts[NSEG] = N; }
    const int4* s4 = (const int4*)seg;
    int N4 = N >> 2;
    for (int i = tid; i < N4; i += stride) {
        int4 s = s4[i];
        int prev = (i == 0) ? s.x : seg[i * 4 - 1];
        if (s.x != prev) seg_starts[s.x] = i * 4;
        if (s.y != s.x) seg_starts[s.y] = i * 4 + 1;
        if (s.z != s.y) seg_starts[s.z] = i * 4 + 2;
        if (s.w != s.z) seg_starts[s.w] = i * 4 + 3;
    }
}

// ---- 1. histogram of (segment, bucket) via per-block LDS hist ----
__global__ void __launch_bounds__(512)
k_hist(const float* __restrict__ x, const int* __restrict__ seg_starts,
       int* __restrict__ counts, int N, float scale) {
    __shared__ int h[2 * NB];
    __shared__ int sst[NSEG + 1];
    int t = threadIdx.x;
    for (int k = t; k < NSEG + 1; k += 512) sst[k] = seg_starts[k];
    for (int k = t; k < 2 * NB; k += 512) h[k] = 0;
    __syncthreads();
    int base = blockIdx.x * HCH;
    int lo = 0, hi = NSEG - 1;
    while (lo < hi) { int mid = (lo + hi) >> 1; if (base < sst[mid + 1]) hi = mid; else lo = mid + 1; }
    int s0 = lo, bnd = sst[lo + 1];
    const float4* x4 = (const float4*)x;
    for (int it = 0; it < HCH / (512 * 4); ++it) {
        int j = (it * 512 + t) * 4;
        int gi = base + j;
        if (gi < N) {
            float4 v = x4[(base >> 2) + it * 512 + t];
            int sel0 = (gi + 0) >= bnd ? NB : 0;
            int sel1 = (gi + 1) >= bnd ? NB : 0;
            int sel2 = (gi + 2) >= bnd ? NB : 0;
            int sel3 = (gi + 3) >= bnd ? NB : 0;
            atomicAdd(&h[sel0 + bucket_of(v.x, scale)], 1);
            atomicAdd(&h[sel1 + bucket_of(v.y, scale)], 1);
            atomicAdd(&h[sel2 + bucket_of(v.z, scale)], 1);
            atomicAdd(&h[sel3 + bucket_of(v.w, scale)], 1);
        }
    }
    __syncthreads();
    for (int k = t; k < 2 * NB; k += 512) {
        int c = h[k];
        if (c > 0) atomicAdd(&counts[(s0 + (k >= NB)) * NB + (k & (NB - 1))], c);
    }
}

// ---- 2. scan over M_TOT counters ----
__global__ void k_scan_partial(const int* __restrict__ counts, int* __restrict__ partials, int M) {
    __shared__ int sdata[256];
    int base = blockIdx.x * 2048;
    int sum = 0;
    for (int k = threadIdx.x; k < 2048; k += 256) {
        int idx = base + k;
        sum += (idx < M) ? counts[idx] : 0;
    }
    sdata[threadIdx.x] = sum;
    __syncthreads();
    for (int off = 128; off > 0; off >>= 1) {
        if (threadIdx.x < off) sdata[threadIdx.x] += sdata[threadIdx.x + off];
        __syncthreads();
    }
    if (threadIdx.x == 0) partials[blockIdx.x] = sdata[0];
}

__global__ void k_scan_final(const int* __restrict__ counts, const int* __restrict__ partials,
                             int* __restrict__ cursor, int* __restrict__ seg_ends, int M) {
    __shared__ int tile[2048];
    __shared__ int sa[256], sb[256];
    int t = threadIdx.x;
    int base = blockIdx.x * 2048;
    int c = 0;
    for (int k = t; k < blockIdx.x; k += 256) c += partials[k];
    sa[t] = c;
    __syncthreads();
    for (int off = 128; off > 0; off >>= 1) {
        if (t < off) sa[t] += sa[t + off];
        __syncthreads();
    }
    int gbase = sa[0];
    __syncthreads();
    for (int k = t; k < 2048; k += 256) {
        int idx = base + k;
        tile[k] = (idx < M) ? counts[idx] : 0;
    }
    __syncthreads();
    int loc[8]; int run = 0;
    for (int k = 0; k < 8; ++k) { loc[k] = run; run += tile[t * 8 + k]; }
    int v = run;
    int* src = sa; int* dst = sb;
    src[t] = v;
    __syncthreads();
    for (int off = 1; off < 256; off <<= 1) {
        int w = src[t] + ((t >= off) ? src[t - off] : 0);
        dst[t] = w;
        __syncthreads();
        int* tmp = src; src = dst; dst = tmp;
    }
    int texcl = src[t] - v;
    for (int k = 0; k < 8; ++k) {
        int idx = base + t * 8 + k;
        if (idx < M) {
            int excl = gbase + texcl + loc[k];
            cursor[idx] = excl;
            if (((idx + 1) & (NB - 1)) == 0)
                seg_ends[((idx + 1) >> LOG_NB) - 1] = excl + tile[t * 8 + k];
        }
    }
}

// ---- 3. scatter with per-block reservation (cursor: starts -> ends) ----
__global__ void __launch_bounds__(512)
k_scatter(const float* __restrict__ x, const int* __restrict__ seg_starts,
          int* __restrict__ cursor, float* __restrict__ sx, int N, float scale) {
    __shared__ int h[2 * NB];
    __shared__ unsigned short lr[SCH];
    __shared__ int sst[NSEG + 1];
    int t = threadIdx.x;
    for (int k = t; k < NSEG + 1; k += 512) sst[k] = seg_starts[k];
    for (int k = t; k < 2 * NB; k += 512) h[k] = 0;
    __syncthreads();
    int base = blockIdx.x * SCH;
    int lo = 0, hi = NSEG - 1;
    while (lo < hi) { int mid = (lo + hi) >> 1; if (base < sst[mid + 1]) hi = mid; else lo = mid + 1; }
    int s0 = lo, bnd = sst[lo + 1];
    const float4* x4 = (const float4*)x;
    for (int it = 0; it < SCH / (512 * 4); ++it) {
        int j = (it * 512 + t) * 4;
        int gi = base + j;
        if (gi < N) {
            float4 v = x4[(base >> 2) + it * 512 + t];
            int g0 = ((gi + 0) >= bnd ? NB : 0) + bucket_of(v.x, scale);
            int g1 = ((gi + 1) >= bnd ? NB : 0) + bucket_of(v.y, scale);
            int g2 = ((gi + 2) >= bnd ? NB : 0) + bucket_of(v.z, scale);
            int g3 = ((gi + 3) >= bnd ? NB : 0) + bucket_of(v.w, scale);
            lr[j + 0] = (unsigned short)atomicAdd(&h[g0], 1);
            lr[j + 1] = (unsigned short)atomicAdd(&h[g1], 1);
            lr[j + 2] = (unsigned short)atomicAdd(&h[g2], 1);
            lr[j + 3] = (unsigned short)atomicAdd(&h[g3], 1);
        }
    }
    __syncthreads();
    for (int k = t; k < 2 * NB; k += 512) {
        int c = h[k];
        if (c > 0) h[k] = atomicAdd(&cursor[(s0 + (k >= NB)) * NB + (k & (NB - 1))], c);
    }
    __syncthreads();
    for (int it = 0; it < SCH / (512 * 4); ++it) {
        int j = (it * 512 + t) * 4;
        int gi = base + j;
        if (gi < N) {
            float4 v = x4[(base >> 2) + it * 512 + t];
            int g0 = ((gi + 0) >= bnd ? NB : 0) + bucket_of(v.x, scale);
            int g1 = ((gi + 1) >= bnd ? NB : 0) + bucket_of(v.y, scale);
            int g2 = ((gi + 2) >= bnd ? NB : 0) + bucket_of(v.z, scale);
            int g3 = ((gi + 3) >= bnd ? NB : 0) + bucket_of(v.w, scale);
            sx[h[g0] + lr[j + 0]] = v.x;
            sx[h[g1] + lr[j + 1]] = v.y;
            sx[h[g2] + lr[j + 2]] = v.z;
            sx[h[g3] + lr[j + 3]] = v.w;
        }
    }
}

// ---- 4. EMD: fine counting-sort path (u64 keys) + R9 fallback paths ----
// smem overlay: sorted path {vwin u64[WCAP+2] | fw u32[1025] | bstart u16[258]}
//               fallback    {win f32[WCAP+8]  | bends i32[BCAP]}
#define SM_BYTES 25120
__global__ void __launch_bounds__(256)
k_emd(const float* __restrict__ sx, const float* __restrict__ y,
      const int* __restrict__ ends, const int* __restrict__ seg_ends,
      float* __restrict__ segSums, int N, float scale, float scale8) {
    __shared__ __align__(16) char smem[SM_BYTES];
    __shared__ int sEnd[NSEG];
    __shared__ int sh[5];
    __shared__ int sa[256], sb[256];
    unsigned long long* vwin = (unsigned long long*)smem;              // 20496 B
    unsigned* fw = (unsigned*)(smem + 20496);                          // 4100 B (1025 words)
    unsigned short* bstart = (unsigned short*)(smem + 20496 + 4104);   // 516 B
    float* win = (float*)smem;                                         // fallback: 10272 B
    int* bends = (int*)(smem + 10272);                                 // fallback: 8208 B

    int tid = threadIdx.x;
    for (int k = tid; k < NSEG; k += 256) sEnd[k] = seg_ends[k];
    __syncthreads();
    int pbase = blockIdx.x * ECHUNK;
    int pend = min(pbase + ECHUNK, N);
    if (tid == 0) {
        float v = sx[pbase];
        int lo = 0, hi = NSEG - 1;
        while (lo < hi) { int mid = (lo + hi) >> 1; if (pbase < sEnd[mid]) hi = mid; else lo = mid + 1; }
        int g = lo * NB + bucket_of(v, scale);
        sh[0] = (g == 0) ? 0 : ends[g - 1];
        sh[2] = lo;
        sh[3] = g;
    }
    if (tid == 255) {
        float v = sx[pend - 1];
        int lo = 0, hi = NSEG - 1;
        while (lo < hi) { int mid = (lo + hi) >> 1; if (pend - 1 < sEnd[mid]) hi = mid; else lo = mid + 1; }
        int g = lo * NB + bucket_of(v, scale);
        sh[1] = ends[g];
        sh[4] = g;
    }
    __syncthreads();
    int wlo = sh[0], whi = sh[1], s0 = sh[2], gfirst = sh[3], glast = sh[4];
    int wsz = whi - wlo;
    bool fits = wsz <= WCAP;
    bool cross = (glast >> LOG_NB) != s0;
    int nb_b = glast - gfirst + 1;
    bool sorted = fits && !cross && nb_b <= SPAN_S - 1;   // f+1 <= 2048 guaranteed

    float acc0 = 0.f, acc1 = 0.f;

    if (sorted) {
        // zero fine counts, load relative bucket starts
        #pragma unroll
        for (int i = 0; i < 4; ++i) fw[tid + i * 256] = 0;
        for (int k = tid; k <= nb_b; k += 256) {
            int g = gfirst - 1 + k;
            int e = (g < 0) ? 0 : ends[g];
            bstart[k] = (unsigned short)(e - wlo);
        }
        __syncthreads();
        // build: global->reg stage + fine histogram
        float fv[10]; unsigned fl[10];
        #pragma unroll
        for (int i = 0; i < 10; ++i) {
            int k = tid + i * 256;
            fl[i] = 0xffffffffu;
            fv[i] = 0.f;
            if (k < wsz) {
                float v = sx[wlo + k];
                fv[i] = v;
                int b = bucket_of(v, scale);
                int b8 = (int)floorf((v + 6.0f) * scale8);
                int sub = b8 - (b << 3);
                sub = sub < 0 ? 0 : (sub > 7 ? 7 : sub);
                int f = (((s0 * NB + b) - gfirst) << 3) + sub;
                unsigned shw = (f & 1) << 4;
                unsigned old = atomicAdd(&fw[f >> 1], 1u << shw);
                unsigned llo = (old >> shw) & 0xffffu;
                fl[i] = ((unsigned)f << 16) | llo;
            }
        }
        __syncthreads();
        // packed-u16 exclusive prefix over 2048 fine bins (1024 words, 4/thread)
        unsigned wv[4]; unsigned run = 0;
        #pragma unroll
        for (int j = 0; j < 4; ++j) {
            unsigned w = fw[tid * 4 + j];
            unsigned c0 = w & 0xffffu, c1 = w >> 16;
            wv[j] = run | ((run + c0) << 16);
            run += c0 + c1;
        }
        int* src = sa; int* dst = sb;
        src[tid] = (int)run;
        __syncthreads();
        for (int off = 1; off < 256; off <<= 1) {
            int w = src[tid] + ((tid >= off) ? src[tid - off] : 0);
            dst[tid] = w;
            __syncthreads();
            int* tmp = src; src = dst; dst = tmp;
        }
        unsigned base = (unsigned)src[tid] - run;
        #pragma unroll
        for (int j = 0; j < 4; ++j) fw[tid * 4 + j] = wv[j] + (base | (base << 16));
        if (tid == 0) fw[1024] = (unsigned)wsz;    // sentinel: prefix[2048]
        __syncthreads();
        // scatter u64 keys (ordered-float hi, window pos lo)
        #pragma unroll
        for (int i = 0; i < 10; ++i) {
            if (fl[i] != 0xffffffffu) {
                int f = (int)(fl[i] >> 16);
                unsigned llo = fl[i] & 0xffffu;
                unsigned pf = (fw[f >> 1] >> ((f & 1) << 4)) & 0xffffu;
                unsigned u = __float_as_uint(fv[i]);
                unsigned m = u ^ ((unsigned)((int)u >> 31) | 0x80000000u);
                int k = tid + i * 256;
                vwin[pf + llo] = ((unsigned long long)m << 32) | (unsigned)k;
            }
        }
        if (tid < 2) vwin[wsz + tid] = 0xffffffffffffffffULL;   // over-read pad
        __syncthreads();
        // rank within fine bin + diff
        #pragma unroll
        for (int i = 0; i < 10; ++i) {
            if (fl[i] == 0xffffffffu) continue;
            int k = tid + i * 256;
            int p = wlo + k;
            if (p < pbase || p >= pend) continue;   // halo element: another block's
            int f = (int)(fl[i] >> 16);
            float v = fv[i];
            unsigned u = __float_as_uint(v);
            unsigned m = u ^ ((unsigned)((int)u >> 31) | 0x80000000u);
            unsigned long long kme = ((unsigned long long)m << 32) | (unsigned)k;
            unsigned fs = (fw[f >> 1] >> ((f & 1) << 4)) & 0xffffu;
            unsigned fe = (fw[(f + 1) >> 1] >> (((f + 1) & 1) << 4)) & 0xffffu;
            int bi = f >> 3;
            unsigned b0 = fw[bi << 2] & 0xffffu;    // prefix of bucket's first fine bin
            int a2 = (int)(fs & ~1u);
            int rank = a2 - (int)b0;                // slots [a2,fs) have strictly smaller keys
            for (int j = a2; j < (int)fe; j += 2) {
                ulonglong2 q = *(const ulonglong2*)&vwin[j];
                rank += (q.x < kme) + (q.y < kme);  // over-read: larger key or pad -> 0
            }
            acc0 += fabsf(v - y[wlo + (int)bstart[bi] + rank]);
        }
    } else {
        // ---- fallback: R9 paths (win + bends staged) ----
        int bcount = nb_b + 1;
        bool useB = fits && bcount <= BCAP;
        bool full = (pend - pbase) == ECHUNK;
        if (fits) {
            for (int k = tid; k < wsz; k += 256) win[k] = sx[wlo + k];
            if (tid < 8) win[wsz + tid] = __builtin_inff();
        }
        if (useB) {
            for (int k = tid; k < bcount; k += 256) {
                int g = gfirst - 1 + k;
                bends[k] = (g < 0) ? 0 : ends[g];
            }
        }
        __syncthreads();
        if (useB && !cross && full) {
            int base_w = pbase - wlo;
            int boff = s0 * NB - gfirst;
            float v[8]; int st[8]; int bq[8]; int idx[8];
            #pragma unroll
            for (int e = 0; e < 8; ++e) v[e] = win[base_w + (e << 8) + tid];
            #pragma unroll
            for (int e = 0; e < 8; ++e) {
                int bi = bucket_of(v[e], scale) + boff;
                st[e] = bends[bi];
                bq[e] = bends[bi + 1] - wlo;
            }
            #pragma unroll
            for (int e = 0; e < 8; ++e) {
                int widx = base_w + (e << 8) + tid;
                float vv = v[e];
                int a = st[e] - wlo;
                int k = a & ~3;
                int rank = k - a;
                int b = bq[e];
                for (; k < b; k += 8) {
                    float4 q0 = *(const float4*)&win[k];
                    float4 q1 = *(const float4*)&win[k + 4];
                    rank += (q0.x < vv) + ((q0.x == vv) & (k + 0 < widx));
                    rank += (q0.y < vv) + ((q0.y == vv) & (k + 1 < widx));
                    rank += (q0.z < vv) + ((q0.z == vv) & (k + 2 < widx));
                    rank += (q0.w < vv) + ((q0.w == vv) & (k + 3 < widx));
                    rank += (q1.x < vv) + ((q1.x == vv) & (k + 4 < widx));
                    rank += (q1.y < vv) + ((q1.y == vv) & (k + 5 < widx));
                    rank += (q1.z < vv) + ((q1.z == vv) & (k + 6 < widx));
                    rank += (q1.w < vv) + ((q1.w == vv) & (k + 7 < widx));
                }
                idx[e] = st[e] + rank;
            }
            #pragma unroll
            for (int e = 0; e < 8; ++e) acc0 += fabsf(v[e] - y[idx[e]]);
        } else if (fits) {
            for (int e = 0; e < ECHUNK / 256; ++e) {
                int p = pbase + (e << 8) + tid;
                if (p >= pend) break;
                int s = s0;
                while (p >= sEnd[s]) ++s;
                int widx = p - wlo;
                float v = win[widx];
                int g = s * NB + bucket_of(v, scale);
                int start, end;
                if (useB) { start = bends[g - gfirst]; end = bends[g - gfirst + 1]; }
                else { start = (g == 0) ? 0 : ends[g - 1]; end = ends[g]; }
                int a = start - wlo, bqq = end - wlo;
                int rank = 0;
                int k = a;
                for (; k < bqq && (k & 3); ++k) { float vj = win[k]; rank += (vj < v) + ((vj == v) & (k < widx)); }
                for (; k + 3 < bqq; k += 4) {
                    float4 q = *(const float4*)&win[k];
                    rank += (q.x < v) + ((q.x == v) & (k + 0 < widx));
                    rank += (q.y < v) + ((q.y == v) & (k + 1 < widx));
                    rank += (q.z < v) + ((q.z == v) & (k + 2 < widx));
                    rank += (q.w < v) + ((q.w == v) & (k + 3 < widx));
                }
                for (; k < bqq; ++k) { float vj = win[k]; rank += (vj < v) + ((vj == v) & (k < widx)); }
                float diff = fabsf(v - y[start + rank]);
                if (s == s0) acc0 += diff;
                else if (s == s0 + 1) acc1 += diff;
                else atomicAdd(&segSums[s], diff);
            }
        } else {
            for (int e = 0; e < ECHUNK / 256; ++e) {
                int p = pbase + (e << 8) + tid;
                if (p >= pend) break;
                int s = s0;
                while (p >= sEnd[s]) ++s;
                float v = sx[p];
                int g = s * NB + bucket_of(v, scale);
                int start = (g == 0) ? 0 : ends[g - 1];
                int end = ends[g];
                int rank = 0;
                for (int j = start; j < end; ++j) { float vj = sx[j]; rank += (vj < v) || (vj == v && j < p); }
                float diff = fabsf(v - y[start + rank]);
                if (s == s0) acc0 += diff;
                else if (s == s0 + 1) acc1 += diff;
                else atomicAdd(&segSums[s], diff);
            }
        }
    }

    for (int off = 32; off > 0; off >>= 1) {
        acc0 += __shfl_xor(acc0, off);
        acc1 += __shfl_xor(acc1, off);
    }
    if ((tid & 63) == 0) {
        if (acc0 != 0.f) atomicAdd(&segSums[s0], acc0);
        if (acc1 != 0.f && s0 + 1 < NSEG) atomicAdd(&segSums[s0 + 1], acc1);
    }
}

// ---- 5. finalize ----
__global__ void k_final(const float* __restrict__ segSums, const int* __restrict__ seg_ends,
                        float* __restrict__ out) {
    __shared__ float red[256];
    int t = threadIdx.x;
    float acc = 0.f;
    for (int s = t; s < NSEG; s += 256) {
        int end = seg_ends[s];
        int st = (s == 0) ? 0 : seg_ends[s - 1];
        float cnt = (float)(end - st);
        acc += segSums[s] / fmaxf(cnt, 1.0f);
    }
    red[t] = acc;
    __syncthreads();
    for (int off = 128; off > 0; off >>= 1) {
        if (t < off) red[t] += red[t + off];
        __syncthreads();
    }
    if (t == 0) out[0] = red[0] * (1.0f / (float)NSEG) * STRENGTH;
}

extern "C" void kernel_launch(void* const* d_in, const int* in_sizes, int n_in,
                              void* d_out, int out_size, void* d_ws, size_t ws_size,
                              hipStream_t stream) {
    const float* x = (const float*)d_in[0];
    const float* y = (const float*)d_in[1];          // initial_sorted
    const int* seg = (const int*)d_in[2];            // segment_ids (sorted)
    int N = in_sizes[0];
    float scale = (float)NB / 12.0f;
    float scale8 = (float)NB * 8.0f / 12.0f;

    char* ws = (char*)d_ws;
    float* sx        = (float*)ws;                        // N floats
    int*   counts    = (int*)(ws + (size_t)N * 4);        // M_TOT ints
    int*   cursor    = counts + M_TOT;                    // M_TOT ints
    int*   partials  = cursor + M_TOT;                    // <=1024 ints
    float* segSums   = (float*)(partials + 1024);         // NSEG floats
    int*   seg_ends  = (int*)(segSums + NSEG);            // NSEG ints
    int*   seg_starts= seg_ends + NSEG;                   // NSEG+1 ints

    int nb = (M_TOT + 2047) / 2048;    // = 400
    int nch_h = (N + HCH - 1) / HCH;
    int nch_s = (N + SCH - 1) / SCH;

    k_bounds<<<512, 256, 0, stream>>>(seg, seg_starts, counts, segSums, N);
    k_hist<<<nch_h, 512, 0, stream>>>(x, seg_starts, counts, N, scale);
    k_scan_partial<<<nb, 256, 0, stream>>>(counts, partials, M_TOT);
    k_scan_final<<<nb, 256, 0, stream>>>(counts, partials, cursor, seg_ends, M_TOT);
    k_scatter<<<nch_s, 512, 0, stream>>>(x, seg_starts, cursor, sx, N, scale);
    k_emd<<<(N + ECHUNK - 1) / ECHUNK, 256, 0, stream>>>(sx, y, cursor, seg_ends, segSums, N, scale, scale8);
    k_final<<<1, 256, 0, stream>>>(segSums, seg_ends, (float*)d_out);
}